// Round 1
// 1378.935 us; speedup vs baseline: 1.4161x; 1.4161x over previous
//
#include <hip/hip_runtime.h>

// ---------------------------------------------------------------------------
// CommNet round 9: switch MFMA path from bf16 hi/lo double-pump to single FP16.
//  R8 counters: conv0 773us, MfmaUtil 33.8, VALUBusy 36.7, HBM 8.7% ->
//  issue/latency bound. Weights were single bf16 (2^-9 rel err) while
//  activations carried hi/lo (2^-17): precision was weight-limited. FP16 gives
//  BOTH operands 2^-12 (absmax should drop) while halving MFMA count and
//  A-load count. Also: conv0 K repacked 21 -> 19 steps (drop 10.7% zero work),
//  h0/h1 8B load pairs merged to one 16B load (aligned(8) vector type).
// Layouts (HW-verified): A[m=lane&15][k=q*8+j], B[n=lane&15][k=q*8+j],
//  D col=lane&15, row=q*4+reg. f16 layout identical to bf16 (same shape).
// ---------------------------------------------------------------------------

typedef __attribute__((ext_vector_type(8)))  _Float16 f16x8;
typedef __attribute__((ext_vector_type(8), aligned(8))) _Float16 f16x8u; // 8B-aligned 16B load
typedef __attribute__((ext_vector_type(4)))  float f32x4;

__device__ __forceinline__ ushort f2h(float f) {
    union { _Float16 h; ushort u; } v;
    v.h = (_Float16)f;                       // v_cvt_f16_f32, RNE
    return v.u;
}

#define MFMA16(A, B, C) __builtin_amdgcn_mfma_f32_16x16x32_f16(A, B, C, 0, 0, 0)

// ---- prep: x [80][4][45^3] fp32 -> hi0 NDHWC padded [80][47][47][48][4] f16
__global__ void pad_input_kernel(const float* __restrict__ x,
                                 ushort* __restrict__ hi)
{
    int t = blockIdx.x * 256 + threadIdx.x;
    const int TOT = 80 * 45 * 45 * 45;
    if (t >= TOT) return;
    int xi = t % 45, r = t / 45;
    int y = r % 45; r /= 45;
    int z = r % 45; int n = r / 45;
    int ib = ((n * 4) * 91125) + z * 2025 + y * 45 + xi;
    int ob = (((n * 47 + z + 1) * 47 + y + 1) * 48 + xi + 1) * 4;
    ushort h4[4];
    #pragma unroll
    for (int ic = 0; ic < 4; ++ic) {
        float v = x[ib + ic * 91125] * (1.f / 255.f);
        h4[ic] = f2h(v);
    }
    *(ushort4*)(hi + ob) = *(ushort4*)h4;
}

// ---- pack conv0 weights [32][4][5][5][5] -> Bp0[19 s][2 ot][64 lane][8 j] f16
// k = ((kz*5+ky)*6+kx)*4 + ic  (kx in [0,6), kx==5 zero; K=600, 19 steps = 608)
__global__ void pack_w0(const float* __restrict__ w, ushort* __restrict__ Bp,
                        int4* __restrict__ Dt)
{
    int t = blockIdx.x * 256 + threadIdx.x;
    if (t < 19 * 2 * 64 * 8) {
        int j = t & 7, l = (t >> 3) & 63, ot = (t >> 9) & 1, s = t >> 10;
        int oc = ot * 16 + (l & 15);
        int k = 32 * s + ((l >> 4) << 3) + j;
        float v = 0.f;
        if (k < 600) {
            int ic = k & 3, t6 = k >> 2;
            int kx = t6 % 6, q = t6 / 6, ky = q % 5, kz = q / 5;
            if (kx < 5) v = w[(oc * 4 + ic) * 125 + kz * 25 + ky * 5 + kx];
        }
        Bp[t] = f2h(v);
    }
    if (t < 19) {
        int dd[4];
        #pragma unroll
        for (int q = 0; q < 4; ++q) {
            int k = 32 * t + 8 * q;
            if (k < 600) {
                int t6 = k >> 2;
                int kx = t6 % 6, qq = t6 / 6;
                dd[q] = (((qq / 5) * 47 + (qq % 5)) * 48 + kx) * 4;  // x-unit=4
            } else dd[q] = 0;
        }
        int4 d; d.x = dd[0]; d.y = dd[1]; d.z = dd[2]; d.w = dd[3];
        Dt[t] = d;
    }
}

// ---- pack conv1 weights [32][32][5][5][5] -> Bp1[126 s][2 ot][64][8] f16
// step s = tap (125 real, 1 zero pad), k = s*32 + ic
__global__ void pack_w1(const float* __restrict__ w, ushort* __restrict__ Bp,
                        int* __restrict__ Dt)
{
    int t = blockIdx.x * 256 + threadIdx.x;
    if (t < 126 * 2 * 64 * 8) {
        int j = t & 7, l = (t >> 3) & 63, ot = (t >> 9) & 1, s = t >> 10;
        int oc = ot * 16 + (l & 15);
        int ic = ((l >> 4) << 3) + j;
        Bp[t] = (s < 125) ? f2h(w[(oc * 32 + ic) * 125 + s]) : (ushort)0;
    }
    if (t < 126) {
        if (t < 125) {
            int kz = t / 25, ky = (t / 5) % 5, kx = t % 5;
            Dt[t] = ((kz * 23 + ky) * 24 + kx) * 32;                 // x-unit=32
        } else Dt[t] = 0;
    }
}

// ---- conv0 MFMA: hi0 [80][47][47][48][4] f16 -> hi1 [80][23][23][24][32] f16
__global__ __launch_bounds__(256)
void conv0_mfma(const ushort* __restrict__ hi0,
                const ushort* __restrict__ Bp, const int4* __restrict__ Dt,
                const float* __restrict__ bias, const float* __restrict__ slope,
                ushort* __restrict__ hi1)
{
    const int n  = blockIdx.z;
    const int pz = blockIdx.x / 21, py = blockIdx.x % 21;
    const int tid = threadIdx.x, lane = tid & 63, w = tid >> 6;
    const int dz = w >> 1, dy = w & 1;
    const int q = lane >> 4, l15 = lane & 15;

    __shared__ float pool[4][21][32];
    const int z0 = 2 * pz + dz, y0 = 2 * py + dy;
    const float sl = slope[0];

    int ab[3];
    #pragma unroll
    for (int xt = 0; xt < 3; ++xt) {
        int x = xt * 16 + l15;
        int xr = x > 41 ? 41 : x;
        ab[xt] = (((n * 47 + z0) * 47 + y0) * 48 + xr) * 4;
    }

    f32x4 acc[3][2] = {};
    const f16x8* Bv = (const f16x8*)Bp;

    constexpr int STEPS = 19;               // 19 = 6*3 + 1 (PF=3 + 1-step tail)
    f16x8 av[3][3], b0v[3], b1v[3];

    auto LOADS = [&](int s, int j) {
        int4 dd = Dt[s];
        int delta = q == 0 ? dd.x : q == 1 ? dd.y : q == 2 ? dd.z : dd.w;
        b0v[j] = Bv[(2 * s) * 64 + lane];
        b1v[j] = Bv[(2 * s + 1) * 64 + lane];
        #pragma unroll
        for (int xt = 0; xt < 3; ++xt)
            av[j][xt] = *(const f16x8u*)(hi0 + ab[xt] + delta);  // one 16B load
    };
    auto COMP = [&](int j) {
        #pragma unroll
        for (int xt = 0; xt < 3; ++xt) {
            acc[xt][0] = MFMA16(av[j][xt], b0v[j], acc[xt][0]);
            acc[xt][1] = MFMA16(av[j][xt], b1v[j], acc[xt][1]);
        }
    };

    LOADS(0, 0); LOADS(1, 1);
    for (int s = 0; s < 18; s += 3) {
        LOADS(s + 2, 2);
        COMP(0);
        LOADS(s + 3, 0);                     // s+3 <= 18 always in-range
        COMP(1);
        if (s + 4 < STEPS) LOADS(s + 4, 1);
        COMP(2);
    }
    COMP(0);                                 // step 18 (buf 0)

    #pragma unroll
    for (int xt = 0; xt < 3; ++xt) {
        int pxe = xt * 8 + 2 * q, pxo = pxe + 1;
        float pe0 = fmaxf(acc[xt][0][0], acc[xt][0][1]);
        float po0 = fmaxf(acc[xt][0][2], acc[xt][0][3]);
        float pe1 = fmaxf(acc[xt][1][0], acc[xt][1][1]);
        float po1 = fmaxf(acc[xt][1][2], acc[xt][1][3]);
        if (pxe < 21) { pool[w][pxe][l15] = pe0; pool[w][pxe][16 + l15] = pe1; }
        if (pxo < 21) { pool[w][pxo][l15] = po0; pool[w][pxo][16 + l15] = po1; }
    }
    __syncthreads();

    for (int t2 = tid; t2 < 672; t2 += 256) {
        int oc = t2 & 31, px = t2 >> 5;
        float v = fmaxf(fmaxf(pool[0][px][oc], pool[1][px][oc]),
                        fmaxf(pool[2][px][oc], pool[3][px][oc]));
        v += bias[oc];
        v = (v >= 0.f) ? v : sl * v;
        int o = (((n * 23 + pz + 1) * 23 + py + 1) * 24 + px + 1) * 32 + oc;
        hi1[o] = f2h(v);
    }
}

// ---- conv1 MFMA: hi1 [80][23][23][24][32] f16 -> P2 fp32 NCDHW padded
// block = (n, pz, py-group of 3); wave = (dz,dy); M flattened over (py_local,x):
// flat = pyl*18 + x in [0,54), 4 m-tiles of 16 (15.6% waste).
__global__ __launch_bounds__(256)
void conv1_mfma(const ushort* __restrict__ hi1,
                const ushort* __restrict__ Bp, const int* __restrict__ Dt,
                const float* __restrict__ bias, const float* __restrict__ slope,
                float* __restrict__ P2)
{
    const int n   = blockIdx.z;
    const int pz  = blockIdx.x / 3, pyg = blockIdx.x % 3;
    const int tid = threadIdx.x, lane = tid & 63, w = tid >> 6;
    const int dz = w >> 1, dy = w & 1;
    const int q = lane >> 4, l15 = lane & 15;

    __shared__ float pool[4][27][32];
    const int z0 = 2 * pz + dz;

    int ab[4];
    #pragma unroll
    for (int t = 0; t < 4; ++t) {
        int flat = t * 16 + l15;
        if (flat > 53) flat = 53;
        int pyl = flat / 18, x = flat - pyl * 18;
        int y0 = 2 * (pyg * 3 + pyl) + dy;
        ab[t] = ((((n * 23 + z0) * 23 + y0) * 24 + x) << 5) + q * 8;
    }

    f32x4 acc[4][2] = {};
    const f16x8* Bv = (const f16x8*)Bp;

    constexpr int STEPS = 126;               // divisible by 3
    f16x8 ahv[3][4], b0v[3], b1v[3];

    auto LOADS = [&](int s, int j) {
        int off = Dt[s];
        b0v[j] = Bv[(2 * s) * 64 + lane];
        b1v[j] = Bv[(2 * s + 1) * 64 + lane];
        #pragma unroll
        for (int t = 0; t < 4; ++t)
            ahv[j][t] = *(const f16x8*)(hi1 + ab[t] + off);  // 16B aligned
    };
    auto COMP = [&](int j) {
        #pragma unroll
        for (int t = 0; t < 4; ++t) {
            acc[t][0] = MFMA16(ahv[j][t], b0v[j], acc[t][0]);
            acc[t][1] = MFMA16(ahv[j][t], b1v[j], acc[t][1]);
        }
    };

    LOADS(0, 0); LOADS(1, 1);
    for (int s = 0; s < STEPS; s += 3) {
        LOADS(s + 2, 2);
        COMP(0);
        if (s + 3 < STEPS) LOADS(s + 3, 0);
        COMP(1);
        if (s + 4 < STEPS) LOADS(s + 4, 1);
        COMP(2);
    }

    // D rows m=q*4+reg of tile t -> flat = t*16+q*4+reg; x-pairs = (reg0,reg1),(reg2,reg3)
    #pragma unroll
    for (int t = 0; t < 4; ++t) {
        int p0 = t * 8 + q * 2;
        float e0 = fmaxf(acc[t][0][0], acc[t][0][1]);
        float o0 = fmaxf(acc[t][0][2], acc[t][0][3]);
        float e1 = fmaxf(acc[t][1][0], acc[t][1][1]);
        float o1 = fmaxf(acc[t][1][2], acc[t][1][3]);
        if (p0 < 27)     { pool[w][p0][l15] = e0;     pool[w][p0][16 + l15] = e1; }
        if (p0 + 1 < 27) { pool[w][p0 + 1][l15] = o0; pool[w][p0 + 1][16 + l15] = o1; }
    }
    __syncthreads();

    for (int t2 = tid; t2 < 864; t2 += 256) {
        int oc = t2 & 31, pr = t2 >> 5;          // pr = pyl*9 + px
        int pyl = pr / 9, px = pr % 9;
        float v = fmaxf(fmaxf(pool[0][pr][oc], pool[1][pr][oc]),
                        fmaxf(pool[2][pr][oc], pool[3][pr][oc]));
        v += bias[oc];
        float s0 = slope[0];
        v = (v >= 0.f) ? v : s0 * v;
        int py = pyg * 3 + pyl;
        P2[(long)n * 32 * 11 * 11 * 12 +
           ((oc * 11 + pz + 1) * 11 + py + 1) * 12 + px + 1] = v;
    }
}

// ---- conv2 (fp32 direct, R4-verified) ----
template<int CIN, int K, int SY, int SXS, int ICS, int SPOOL, int PX,
         int OXS, int OPAD>
__global__ __launch_bounds__(256, 2)
void conv_pool_kernel(const float* __restrict__ in,
                      const float* __restrict__ w,
                      const float* __restrict__ bias,
                      const float* __restrict__ slope,
                      float* __restrict__ out,
                      float scale)
{
    constexpr int NX  = 2 * PX;
    constexpr int LX  = NX + K - 1;
    constexpr int LX2 = (LX + 1) / 2;
    constexpr int XT  = SPOOL / PX;
    constexpr int OD  = SPOOL + 2 * OPAD;

    const int oc   = blockIdx.y;
    const int n    = blockIdx.z;
    const int COUT = gridDim.y;

    int idx = blockIdx.x * blockDim.x + threadIdx.x;
    const int POS = XT * SPOOL * SPOOL;
    if (idx >= POS) return;

    int xt  = idx % XT;
    int py  = (idx / XT) % SPOOL;
    int pz  = idx / (XT * SPOOL);
    int px0 = xt * PX;

    const float* inb = in + (long)n * CIN * ICS + (2 * pz * SY + 2 * py) * SXS + 2 * px0;
    const float* wb  = w + (long)oc * CIN * K * K * K;

    float acc[2][2][NX] = {};

    #pragma unroll 1
    for (int ic = 0; ic < CIN; ++ic) {
        const float* inc = inb + (long)ic * ICS;
        const float* wic = wb + ic * K * K * K;
        #pragma unroll
        for (int tz = 0; tz < K + 1; ++tz) {
            #pragma unroll
            for (int ty = 0; ty < K + 1; ++ty) {
                const float2* rp = (const float2*)(inc + (tz * SY + ty) * SXS);
                float row[LX2 * 2];
                #pragma unroll
                for (int i = 0; i < LX2; ++i) {
                    float2 t = rp[i];
                    row[2 * i] = t.x; row[2 * i + 1] = t.y;
                }
                #pragma unroll
                for (int dzz = 0; dzz < 2; ++dzz) {
                    if (tz - dzz < 0 || tz - dzz >= K) continue;
                    #pragma unroll
                    for (int dyy = 0; dyy < 2; ++dyy) {
                        if (ty - dyy < 0 || ty - dyy >= K) continue;
                        const float* wrow = wic + ((tz - dzz) * K + (ty - dyy)) * K;
                        #pragma unroll
                        for (int kx = 0; kx < K; ++kx) {
                            float wv = wrow[kx];
                            #pragma unroll
                            for (int dx = 0; dx < NX; ++dx)
                                acc[dzz][dyy][dx] += wv * row[kx + dx];
                        }
                    }
                }
            }
        }
    }

    float b = bias[oc];
    float a = slope[0];
    long ob = ((long)n * COUT + oc) * (OD * OD * OXS)
            + (long)(pz + OPAD) * (OD * OXS) + (py + OPAD) * OXS + OPAD + px0;
    #pragma unroll
    for (int j = 0; j < PX; ++j) {
        float m = -3.4e38f;
        #pragma unroll
        for (int dzz = 0; dzz < 2; ++dzz)
            #pragma unroll
            for (int dyy = 0; dyy < 2; ++dyy)
                #pragma unroll
                for (int dx = 0; dx < 2; ++dx) {
                    float v = acc[dzz][dyy][2 * j + dx] * scale + b;
                    v = (v >= 0.f) ? v : a * v;
                    m = fmaxf(m, v);
                }
        out[ob + j] = m;
    }
}

// ---- conv3 (fp32 direct) ----
__global__ void conv3_kernel(const float* __restrict__ in,
                             const float* __restrict__ w,
                             const float* __restrict__ bias,
                             const float* __restrict__ slope,
                             float* __restrict__ out)
{
    int idx = blockIdx.x * blockDim.x + threadIdx.x;
    const int TOTAL = 80 * 64 * 8;
    if (idx >= TOTAL) return;
    int p  = idx & 7;
    int oc = (idx >> 3) & 63;
    int n  = idx >> 9;
    int ox = p & 1, oy = (p >> 1) & 1, oz = p >> 2;

    const float* inb = in + (long)n * 64 * 64;
    const float* wb  = w + (long)oc * 64 * 27;

    float acc = 0.f;
    for (int ic = 0; ic < 64; ++ic) {
        const float* inc = inb + ic * 64;
        const float* wc  = wb + ic * 27;
        #pragma unroll
        for (int kz = 0; kz < 3; ++kz)
            #pragma unroll
            for (int ky = 0; ky < 3; ++ky)
                #pragma unroll
                for (int kx = 0; kx < 3; ++kx)
                    acc += wc[(kz * 3 + ky) * 3 + kx] *
                           inc[((oz + kz) * 4 + (oy + ky)) * 4 + (ox + kx)];
    }
    float v = acc + bias[oc];
    float a = slope[0];
    v = (v >= 0.f) ? v : a * v;
    out[idx] = v;
}

// ---- comm-FC ----
template<int D, int O, bool PRELU_ON>
__global__ void comm_fc_kernel(const float* __restrict__ feat,
                               const float* __restrict__ w,
                               const float* __restrict__ bias,
                               const float* __restrict__ slope,
                               float* __restrict__ out)
{
    const int a = blockIdx.x;
    const int b = blockIdx.y;

    __shared__ __align__(16) float cat[2 * D];
    for (int i = threadIdx.x; i < D; i += blockDim.x) {
        float m = 0.f;
        #pragma unroll
        for (int aa = 0; aa < 5; ++aa) m += feat[(b * 5 + aa) * D + i];
        cat[i]     = feat[(b * 5 + a) * D + i];
        cat[D + i] = m * 0.2f;
    }
    __syncthreads();

    for (int o = threadIdx.x; o < O; o += blockDim.x) {
        const float4* wr = (const float4*)(w + ((long)(a * O) + o) * 2 * D);
        const float4* cr = (const float4*)cat;
        float acc = 0.f;
        for (int i = 0; i < 2 * D / 4; ++i) {
            float4 wv = wr[i];
            float4 cv = cr[i];
            acc += wv.x * cv.x + wv.y * cv.y + wv.z * cv.z + wv.w * cv.w;
        }
        acc += bias[a * O + o];
        if constexpr (PRELU_ON) {
            float s = slope[0];
            acc = (acc >= 0.f) ? acc : s * acc;
        }
        out[(b * 5 + a) * O + o] = acc;
    }
}

extern "C" void kernel_launch(void* const* d_in, const int* in_sizes, int n_in,
                              void* d_out, int out_size, void* d_ws, size_t ws_size,
                              hipStream_t stream)
{
    const float* x    = (const float*)d_in[0];
    const float* c0w  = (const float*)d_in[1];
    const float* c0b  = (const float*)d_in[2];
    const float* p0   = (const float*)d_in[3];
    const float* c1w  = (const float*)d_in[4];
    const float* c1b  = (const float*)d_in[5];
    const float* p1   = (const float*)d_in[6];
    const float* c2w  = (const float*)d_in[7];
    const float* c2b  = (const float*)d_in[8];
    const float* p2   = (const float*)d_in[9];
    const float* c3w  = (const float*)d_in[10];
    const float* c3b  = (const float*)d_in[11];
    const float* p3   = (const float*)d_in[12];
    const float* f1w  = (const float*)d_in[13];
    const float* f1b  = (const float*)d_in[14];
    const float* p4   = (const float*)d_in[15];
    const float* f2w  = (const float*)d_in[16];
    const float* f2b  = (const float*)d_in[17];
    const float* p5   = (const float*)d_in[18];
    const float* f3w  = (const float*)d_in[19];
    const float* f3b  = (const float*)d_in[20];

    char* ws = (char*)d_ws;
    ushort* hi0  = (ushort*)(ws);                         // 33,930,240 el f16
    ushort* hi1  = (ushort*)(ws + 67860480);              // 32,501,760 el f16
    float*  P2   = (float*) (ws + 132864000);             //  3,717,120 el
    float*  P3   = (float*) (ws + 147732480);             //    327,680 el
    float*  feat0= (float*) (ws + 149043200);
    float*  feat1= (float*) (ws + 149207040);
    float*  feat2= (float*) (ws + 149288960);
    ushort* Bp0  = (ushort*)(ws + 149329920);             // 19,456 el
    ushort* Bp1  = (ushort*)(ws + 149368832);             // 129,024 el
    int4*   Dt0  = (int4*)  (ws + 149626880);             // 19
    int*    Dt1  = (int*)   (ws + 149627184);             // 126

    // zero halos of hi0/hi1 + all of P2
    hipMemsetAsync(ws, 0, 147732480, stream);

    pack_w0<<<76, 256, 0, stream>>>(c0w, Bp0, Dt0);
    pack_w1<<<504, 256, 0, stream>>>(c1w, Bp1, Dt1);
    pad_input_kernel<<<(7290000 + 255) / 256, 256, 0, stream>>>(x, hi0);

    conv0_mfma<<<dim3(441, 1, 80), 256, 0, stream>>>(hi0, Bp0, Dt0,
                                                     c0b, p0, hi1);
    conv1_mfma<<<dim3(27, 1, 80), 256, 0, stream>>>(hi1, Bp1, Dt1,
                                                    c1b, p1, P2);

    conv_pool_kernel<32, 4, 11, 12, 1452, 4, 1, 4, 0>
        <<<dim3(1, 64, 80), dim3(64), 0, stream>>>(P2, c2w, c2b, p2, P3, 1.f);

    conv3_kernel<<<dim3(160), dim3(256), 0, stream>>>(P3, c3w, c3b, p3, feat0);

    comm_fc_kernel<512, 256, true>
        <<<dim3(5, 16), dim3(256), 0, stream>>>(feat0, f1w, f1b, p4, feat1);
    comm_fc_kernel<256, 128, true>
        <<<dim3(5, 16), dim3(256), 0, stream>>>(feat1, f2w, f2b, p5, feat2);
    comm_fc_kernel<128, 6, false>
        <<<dim3(5, 16), dim3(64), 0, stream>>>(feat2, f3w, f3b, nullptr, (float*)d_out);
}